// Round 1
// baseline (3970.199 us; speedup 1.0000x reference)
//
#include <hip/hip_runtime.h>

#define N_OUT   128
#define IN_DIM  128
#define EDGE_D  16
#define K_EDGE  144   // 128 + 16
#define K_NODE  256   // 128 + 128

// ---------------- edge message + atomic scatter ----------------
// block = 256 threads = 2 halves x 128 cols; each half processes 4 edges/iter.
// W cached in LDS as float4-packed over k (conflict-free ds_read_b128).
__global__ __launch_bounds__(256, 2) void edge_msg_kernel(
    const float* __restrict__ xin,
    const int*   __restrict__ src,
    const int*   __restrict__ dst,
    const float* __restrict__ ea,
    const float* __restrict__ W,     // [144][128] row-major
    const float* __restrict__ bias,  // [128]
    float* __restrict__ agg,         // [N][128], pre-zeroed
    float* __restrict__ cnt,         // [N], pre-zeroed
    int nEdges)
{
    __shared__ float4 sW[(K_EDGE/4) * N_OUT];          // 73728 B
    __shared__ __align__(16) float sx[2][4][K_EDGE];   // 4608 B
    const int tid  = threadIdx.x;
    const int half = tid >> 7;
    const int t    = tid & 127;

    // stage W transposed into k4-packed float4
    for (int idx = tid; idx < (K_EDGE/4)*N_OUT; idx += 256) {
        int k4 = idx >> 7, col = idx & 127;
        float4 w;
        w.x = W[(k4*4+0)*N_OUT + col];
        w.y = W[(k4*4+1)*N_OUT + col];
        w.z = W[(k4*4+2)*N_OUT + col];
        w.w = W[(k4*4+3)*N_OUT + col];
        sW[idx] = w;
    }
    const float b = bias[t];
    __syncthreads();

    const int nQuad = (nEdges + 3) >> 2;
    for (int qbase = blockIdx.x*2; qbase < nQuad; qbase += gridDim.x*2) {
        const int quad   = qbase + half;
        const bool active = (quad < nQuad);
        const int e0 = quad * 4;
        const int ne = active ? min(4, nEdges - e0) : 0;

        for (int j = 0; j < ne; ++j) {
            int e = e0 + j;
            int s = src[e];
            sx[half][j][t] = xin[(size_t)s*IN_DIM + t];
            if (t < EDGE_D) sx[half][j][IN_DIM + t] = ea[(size_t)e*EDGE_D + t];
        }
        __syncthreads();

        float acc0 = b, acc1 = b, acc2 = b, acc3 = b;
        if (active) {
            const float4* x0 = (const float4*)sx[half][0];
            const float4* x1 = (const float4*)sx[half][1];
            const float4* x2 = (const float4*)sx[half][2];
            const float4* x3 = (const float4*)sx[half][3];
            #pragma unroll
            for (int k4 = 0; k4 < K_EDGE/4; ++k4) {
                float4 wv = sW[k4*N_OUT + t];
                float4 a;
                a = x0[k4]; acc0 += a.x*wv.x + a.y*wv.y + a.z*wv.z + a.w*wv.w;
                a = x1[k4]; acc1 += a.x*wv.x + a.y*wv.y + a.z*wv.z + a.w*wv.w;
                a = x2[k4]; acc2 += a.x*wv.x + a.y*wv.y + a.z*wv.z + a.w*wv.w;
                a = x3[k4]; acc3 += a.x*wv.x + a.y*wv.y + a.z*wv.z + a.w*wv.w;
            }
        }

        if (0 < ne) atomicAdd(&agg[(size_t)dst[e0+0]*N_OUT + t], fmaxf(acc0, 0.0f));
        if (1 < ne) atomicAdd(&agg[(size_t)dst[e0+1]*N_OUT + t], fmaxf(acc1, 0.0f));
        if (2 < ne) atomicAdd(&agg[(size_t)dst[e0+2]*N_OUT + t], fmaxf(acc2, 0.0f));
        if (3 < ne) atomicAdd(&agg[(size_t)dst[e0+3]*N_OUT + t], fmaxf(acc3, 0.0f));
        if (t == 0) {
            for (int j = 0; j < ne; ++j) atomicAdd(&cnt[dst[e0+j]], 1.0f);
        }
        __syncthreads();
    }
}

// ---------------- node update: relu(concat(h, agg/cnt) @ U) ----------------
// block = 512 threads = 4 groups x 128 cols; each group processes 4 nodes/iter.
__global__ __launch_bounds__(512, 2) void node_upd_kernel(
    const float* __restrict__ hin,
    const float* __restrict__ agg,
    const float* __restrict__ cnt,
    const float* __restrict__ U,     // [256][128] row-major
    float* __restrict__ out,
    int nNodes)
{
    __shared__ float4 sU[(K_NODE/4) * N_OUT];          // 131072 B
    __shared__ __align__(16) float sc[4][4][K_NODE];   // 16384 B
    const int tid = threadIdx.x;
    const int g   = tid >> 7;
    const int t   = tid & 127;

    for (int idx = tid; idx < (K_NODE/4)*N_OUT; idx += 512) {
        int k4 = idx >> 7, col = idx & 127;
        float4 u;
        u.x = U[(k4*4+0)*N_OUT + col];
        u.y = U[(k4*4+1)*N_OUT + col];
        u.z = U[(k4*4+2)*N_OUT + col];
        u.w = U[(k4*4+3)*N_OUT + col];
        sU[idx] = u;
    }
    __syncthreads();

    const int ngrp = (nNodes + 3) >> 2;
    for (int gbase = blockIdx.x*4; gbase < ngrp; gbase += gridDim.x*4) {
        const int grp = gbase + g;
        const bool active = (grp < ngrp);
        const int i0 = grp * 4;
        const int nn = active ? min(4, nNodes - i0) : 0;

        for (int j = 0; j < nn; ++j) {
            int i = i0 + j;
            sc[g][j][t] = hin[(size_t)i*N_OUT + t];
            float rc = 1.0f / fmaxf(cnt[i], 1.0f);
            sc[g][j][N_OUT + t] = agg[(size_t)i*N_OUT + t] * rc;
        }
        __syncthreads();

        float acc0 = 0.f, acc1 = 0.f, acc2 = 0.f, acc3 = 0.f;
        if (active) {
            const float4* c0 = (const float4*)sc[g][0];
            const float4* c1 = (const float4*)sc[g][1];
            const float4* c2 = (const float4*)sc[g][2];
            const float4* c3 = (const float4*)sc[g][3];
            #pragma unroll
            for (int k4 = 0; k4 < K_NODE/4; ++k4) {
                float4 uv = sU[k4*N_OUT + t];
                float4 a;
                a = c0[k4]; acc0 += a.x*uv.x + a.y*uv.y + a.z*uv.z + a.w*uv.w;
                a = c1[k4]; acc1 += a.x*uv.x + a.y*uv.y + a.z*uv.z + a.w*uv.w;
                a = c2[k4]; acc2 += a.x*uv.x + a.y*uv.y + a.z*uv.z + a.w*uv.w;
                a = c3[k4]; acc3 += a.x*uv.x + a.y*uv.y + a.z*uv.z + a.w*uv.w;
            }
        }

        if (0 < nn) out[(size_t)(i0+0)*N_OUT + t] = fmaxf(acc0, 0.0f);
        if (1 < nn) out[(size_t)(i0+1)*N_OUT + t] = fmaxf(acc1, 0.0f);
        if (2 < nn) out[(size_t)(i0+2)*N_OUT + t] = fmaxf(acc2, 0.0f);
        if (3 < nn) out[(size_t)(i0+3)*N_OUT + t] = fmaxf(acc3, 0.0f);
        __syncthreads();
    }
}

extern "C" void kernel_launch(void* const* d_in, const int* in_sizes, int n_in,
                              void* d_out, int out_size, void* d_ws, size_t ws_size,
                              hipStream_t stream)
{
    const float* x  = (const float*)d_in[0];
    const int*   ei = (const int*)  d_in[1];
    const float* ea = (const float*)d_in[2];
    const float* W1 = (const float*)d_in[3];
    const float* b1 = (const float*)d_in[4];
    const float* U1 = (const float*)d_in[5];
    const float* W2 = (const float*)d_in[6];
    const float* b2 = (const float*)d_in[7];
    const float* U2 = (const float*)d_in[8];
    // d_in[9] = k (fixed at 3 by the reference)

    const int nE     = in_sizes[1] / 2;
    const int nNodes = in_sizes[0] / IN_DIM;
    const int* srcp = ei;
    const int* dstp = ei + nE;

    float* agg  = (float*)d_ws;
    float* cntp = agg + (size_t)nNodes * N_OUT;
    float* h    = cntp + nNodes;
    float* outp = (float*)d_out;

    auto run_layer = [&](const float* xin, const float* W, const float* b,
                         const float* U, float* xout) {
        hipMemsetAsync(agg,  0, (size_t)nNodes * N_OUT * sizeof(float), stream);
        hipMemsetAsync(cntp, 0, (size_t)nNodes * sizeof(float), stream);
        edge_msg_kernel<<<1024, 256, 0, stream>>>(xin, srcp, dstp, ea, W, b, agg, cntp, nE);
        node_upd_kernel<<<256, 512, 0, stream>>>(xin, agg, cntp, U, xout, nNodes);
    };

    run_layer(x, W1, b1, U1, h);     // conv1
    run_layer(h, W2, b2, U2, h);     // conv2 (in-place safe per-row)
    run_layer(h, W2, b2, U2, outp);  // conv3 -> d_out
}

// Round 2
// 1885.548 us; speedup vs baseline: 2.1056x; 2.1056x over previous
//
#include <hip/hip_runtime.h>

#define N_OUT   128
#define IN_DIM  128
#define EDGE_D  16
#define K_EDGE  144   // 128 + 16
#define K4E     36    // K_EDGE / 4
#define SXROW   37    // padded A-tile row, in float4 units (pad kills 4-way bank conflict)
#define TILE_E  128
#define K_NODE  256   // 128 + 128

// ---------------- edge GEMM + atomic scatter ----------------
// 512 threads; tile = 128 edges x 128 cols; thread tile = 4 edges x 8 cols
// (cols interleaved: col = cx + 16*cc -> W reads 2-way bank = free).
// W k4-packed in LDS; A-tile gathered to LDS with register double-buffering.
__global__ __launch_bounds__(512, 1) void edge_gemm_kernel(
    const float* __restrict__ xin,
    const int*   __restrict__ src,
    const int*   __restrict__ dst,
    const float* __restrict__ ea,
    const float* __restrict__ W,     // [144][128] row-major
    const float* __restrict__ bias,  // [128]
    float* __restrict__ agg,         // [N][128], pre-zeroed
    int nEdges, int nTiles)
{
    __shared__ float4 sW[K4E * N_OUT];       // 73728 B
    __shared__ float4 sx[TILE_E * SXROW];    // 75776 B   (total 149504 <= 160K)
    const int tid = threadIdx.x;

    // stage W transposed into k4-packed float4: sW[k4*128 + col]
    for (int idx = tid; idx < K4E * N_OUT; idx += 512) {
        int k4 = idx >> 7, col = idx & 127;
        float4 w;
        w.x = W[(k4*4+0)*N_OUT + col];
        w.y = W[(k4*4+1)*N_OUT + col];
        w.z = W[(k4*4+2)*N_OUT + col];
        w.w = W[(k4*4+3)*N_OUT + col];
        sW[idx] = w;
    }

    const int cx = tid & 15;   // col base; thread cols = cx + 16*cc, cc=0..7
    const int ey = tid >> 4;   // 0..31;   thread edges = ey*4 + ee, ee=0..3

    float bcol[8];
    #pragma unroll
    for (int cc = 0; cc < 8; ++cc) bcol[cc] = bias[cx + 16*cc];

    // register prefetch buffer: 128 edges * 36 float4 / 512 thr = 9 per thread
    float4 r[9];
    auto prefetch = [&](int tile) {
        if (tile >= nTiles) return;
        const int ebase = tile * TILE_E;
        #pragma unroll
        for (int t = 0; t < 9; ++t) {
            int idx = tid + t*512;
            int el  = idx / 36, j = idx - el*36;
            int e   = ebase + el;
            float4 v = make_float4(0.f, 0.f, 0.f, 0.f);
            if (e < nEdges) {
                if (j < 32) v = ((const float4*)xin)[(size_t)src[e]*32 + j];
                else        v = ((const float4*)ea)[(size_t)e*4 + (j - 32)];
            }
            r[t] = v;
        }
    };

    prefetch(blockIdx.x);

    for (int tile = blockIdx.x; tile < nTiles; tile += gridDim.x) {
        __syncthreads();   // previous tile's readers done (also fences sW on iter 0)
        #pragma unroll
        for (int t = 0; t < 9; ++t) {
            int idx = tid + t*512;
            int el  = idx / 36, j = idx - el*36;
            sx[el*SXROW + j] = r[t];
        }
        __syncthreads();   // A-tile visible

        prefetch(tile + gridDim.x);   // global loads overlap compute below

        float acc[4][8];
        #pragma unroll
        for (int ee = 0; ee < 4; ++ee)
            #pragma unroll
            for (int cc = 0; cc < 8; ++cc) acc[ee][cc] = bcol[cc];

        #pragma unroll 6
        for (int k4 = 0; k4 < K4E; ++k4) {
            float4 wv[8], av[4];
            #pragma unroll
            for (int cc = 0; cc < 8; ++cc) wv[cc] = sW[k4*N_OUT + cx + 16*cc];
            #pragma unroll
            for (int ee = 0; ee < 4; ++ee) av[ee] = sx[(ey*4+ee)*SXROW + k4];
            #pragma unroll
            for (int ee = 0; ee < 4; ++ee) {
                #pragma unroll
                for (int cc = 0; cc < 8; ++cc) {
                    acc[ee][cc] += av[ee].x*wv[cc].x + av[ee].y*wv[cc].y
                                 + av[ee].z*wv[cc].z + av[ee].w*wv[cc].w;
                }
            }
        }

        const int ebase = tile * TILE_E;
        #pragma unroll
        for (int ee = 0; ee < 4; ++ee) {
            int e = ebase + ey*4 + ee;
            if (e < nEdges) {
                float* arow = &agg[(size_t)dst[e]*N_OUT];
                #pragma unroll
                for (int cc = 0; cc < 8; ++cc)
                    atomicAdd(&arow[cx + 16*cc], fmaxf(acc[ee][cc], 0.0f));
            }
        }
    }
}

// ---------------- degree count (dst is layer-invariant: run once) ----------------
__global__ void cnt_kernel(const int* __restrict__ dst, float* __restrict__ cnt, int nE)
{
    int i = blockIdx.x * blockDim.x + threadIdx.x;
    if (i < nE) atomicAdd(&cnt[dst[i]], 1.0f);
}

// ---------------- node update: relu(concat(h, agg/cnt) @ U) ----------------
__global__ __launch_bounds__(512, 2) void node_upd_kernel(
    const float* __restrict__ hin,
    const float* __restrict__ agg,
    const float* __restrict__ cnt,
    const float* __restrict__ U,     // [256][128] row-major
    float* __restrict__ out,
    int nNodes)
{
    __shared__ float4 sU[(K_NODE/4) * N_OUT];          // 131072 B
    __shared__ __align__(16) float sc[4][4][K_NODE];   // 16384 B
    const int tid = threadIdx.x;
    const int g   = tid >> 7;
    const int t   = tid & 127;

    for (int idx = tid; idx < (K_NODE/4)*N_OUT; idx += 512) {
        int k4 = idx >> 7, col = idx & 127;
        float4 u;
        u.x = U[(k4*4+0)*N_OUT + col];
        u.y = U[(k4*4+1)*N_OUT + col];
        u.z = U[(k4*4+2)*N_OUT + col];
        u.w = U[(k4*4+3)*N_OUT + col];
        sU[idx] = u;
    }
    __syncthreads();

    const int ngrp = (nNodes + 3) >> 2;
    for (int gbase = blockIdx.x*4; gbase < ngrp; gbase += gridDim.x*4) {
        const int grp = gbase + g;
        const bool active = (grp < ngrp);
        const int i0 = grp * 4;
        const int nn = active ? min(4, nNodes - i0) : 0;

        for (int j = 0; j < nn; ++j) {
            int i = i0 + j;
            sc[g][j][t] = hin[(size_t)i*N_OUT + t];
            float rc = 1.0f / fmaxf(cnt[i], 1.0f);
            sc[g][j][N_OUT + t] = agg[(size_t)i*N_OUT + t] * rc;
        }
        __syncthreads();

        float acc0 = 0.f, acc1 = 0.f, acc2 = 0.f, acc3 = 0.f;
        if (active) {
            const float4* c0 = (const float4*)sc[g][0];
            const float4* c1 = (const float4*)sc[g][1];
            const float4* c2 = (const float4*)sc[g][2];
            const float4* c3 = (const float4*)sc[g][3];
            #pragma unroll
            for (int k4 = 0; k4 < K_NODE/4; ++k4) {
                float4 uv = sU[k4*N_OUT + t];
                float4 a;
                a = c0[k4]; acc0 += a.x*uv.x + a.y*uv.y + a.z*uv.z + a.w*uv.w;
                a = c1[k4]; acc1 += a.x*uv.x + a.y*uv.y + a.z*uv.z + a.w*uv.w;
                a = c2[k4]; acc2 += a.x*uv.x + a.y*uv.y + a.z*uv.z + a.w*uv.w;
                a = c3[k4]; acc3 += a.x*uv.x + a.y*uv.y + a.z*uv.z + a.w*uv.w;
            }
        }

        if (0 < nn) out[(size_t)(i0+0)*N_OUT + t] = fmaxf(acc0, 0.0f);
        if (1 < nn) out[(size_t)(i0+1)*N_OUT + t] = fmaxf(acc1, 0.0f);
        if (2 < nn) out[(size_t)(i0+2)*N_OUT + t] = fmaxf(acc2, 0.0f);
        if (3 < nn) out[(size_t)(i0+3)*N_OUT + t] = fmaxf(acc3, 0.0f);
        __syncthreads();
    }
}

extern "C" void kernel_launch(void* const* d_in, const int* in_sizes, int n_in,
                              void* d_out, int out_size, void* d_ws, size_t ws_size,
                              hipStream_t stream)
{
    const float* x  = (const float*)d_in[0];
    const int*   ei = (const int*)  d_in[1];
    const float* ea = (const float*)d_in[2];
    const float* W1 = (const float*)d_in[3];
    const float* b1 = (const float*)d_in[4];
    const float* U1 = (const float*)d_in[5];
    const float* W2 = (const float*)d_in[6];
    const float* b2 = (const float*)d_in[7];
    const float* U2 = (const float*)d_in[8];

    const int nE     = in_sizes[1] / 2;
    const int nNodes = in_sizes[0] / IN_DIM;
    const int nTiles = (nE + TILE_E - 1) / TILE_E;
    const int* srcp = ei;
    const int* dstp = ei + nE;

    float* agg  = (float*)d_ws;
    float* cntp = agg + (size_t)nNodes * N_OUT;
    float* h    = cntp + nNodes;
    float* outp = (float*)d_out;

    // degree counts: dst is the same for all layers -> compute once
    hipMemsetAsync(cntp, 0, (size_t)nNodes * sizeof(float), stream);
    cnt_kernel<<<(nE + 255)/256, 256, 0, stream>>>(dstp, cntp, nE);

    auto run_layer = [&](const float* xin, const float* W, const float* b,
                         const float* U, float* xout) {
        hipMemsetAsync(agg, 0, (size_t)nNodes * N_OUT * sizeof(float), stream);
        edge_gemm_kernel<<<256, 512, 0, stream>>>(xin, srcp, dstp, ea, W, b, agg, nE, nTiles);
        node_upd_kernel<<<256, 512, 0, stream>>>(xin, agg, cntp, U, xout, nNodes);
    };

    run_layer(x, W1, b1, U1, h);     // conv1
    run_layer(h, W2, b2, U2, h);     // conv2 (in-place safe per-row)
    run_layer(h, W2, b2, U2, outp);  // conv3 -> d_out
}

// Round 3
// 1025.905 us; speedup vs baseline: 3.8699x; 1.8379x over previous
//
#include <hip/hip_runtime.h>

#define N_OUT   128
#define IN_DIM  128
#define EDGE_D  16
#define K_NODE  256   // 128 + 128
#define TILE    128   // edges per tile
#define KPAD    160   // 144 padded to mult of 32

typedef short  s16x8 __attribute__((ext_vector_type(8)));
typedef float  f32x4 __attribute__((ext_vector_type(4)));

__device__ __forceinline__ ushort f2bf(float f) {
    unsigned u = __float_as_uint(f);
    return (ushort)((u + 0x7FFFu + ((u >> 16) & 1u)) >> 16);   // RNE
}
__device__ __forceinline__ float bf2f(ushort h) {
    return __uint_as_float(((unsigned)h) << 16);
}

// ---------------- CSR build (once; src/dst are layer-invariant) ----------------
__global__ void hist_kernel(const int* __restrict__ dst, int* __restrict__ hist, int nE) {
    int e = blockIdx.x * blockDim.x + threadIdx.x;
    if (e < nE) atomicAdd(&hist[dst[e]], 1);
}

__global__ void scan_kernel(const int* __restrict__ hist, int* __restrict__ rowptr, int n) {
    __shared__ int buf[1024];
    __shared__ int carry;
    if (threadIdx.x == 0) carry = 0;
    __syncthreads();
    int nch = (n + 1023) >> 10;
    for (int ch = 0; ch < nch; ++ch) {
        int i = (ch << 10) + threadIdx.x;
        int v = (i < n) ? hist[i] : 0;
        buf[threadIdx.x] = v;
        __syncthreads();
        for (int off = 1; off < 1024; off <<= 1) {
            int t = (threadIdx.x >= (unsigned)off) ? buf[threadIdx.x - off] : 0;
            __syncthreads();
            buf[threadIdx.x] += t;
            __syncthreads();
        }
        if (i < n) rowptr[i] = carry + buf[threadIdx.x] - v;   // exclusive
        __syncthreads();
        if (threadIdx.x == 1023) carry += buf[1023];
        __syncthreads();
    }
}

__global__ void scatter_kernel(const int* __restrict__ src, const int* __restrict__ dst,
                               const int* __restrict__ rowptr, int* __restrict__ cursor,
                               int* __restrict__ eperm, int* __restrict__ srcS,
                               int* __restrict__ dstS, int nE) {
    int e = blockIdx.x * blockDim.x + threadIdx.x;
    if (e < nE) {
        int d = dst[e];
        int pos = rowptr[d] + atomicAdd(&cursor[d], 1);
        eperm[pos] = e;
        dstS[pos]  = d;
        srcS[pos]  = src[e];
    }
}

__global__ void deg_kernel(const int* __restrict__ hist, float* __restrict__ cntf, int n) {
    int i = blockIdx.x * blockDim.x + threadIdx.x;
    if (i < n) cntf[i] = (float)hist[i];
}

// W [144][128] f32 -> Wh/Wl [160][128] bf16 (split hi/lo, zero-padded rows)
__global__ void wprep_kernel(const float* __restrict__ W, ushort* __restrict__ Wh,
                             ushort* __restrict__ Wl, int K) {
    int i = blockIdx.x * blockDim.x + threadIdx.x;
    if (i >= KPAD * N_OUT) return;
    int k = i >> 7;
    float f = (k < K) ? W[i] : 0.0f;
    ushort h = f2bf(f);
    Wh[i] = h;
    Wl[i] = f2bf(f - bf2f(h));
}

// ---------------- edge GEMM (split-bf16 MFMA) + CSR segment-reduce ----------------
// 512 thr = 8 waves. Wave w owns cols 16w..16w+15; W frags in registers.
// Tile = 128 sorted-edge positions x 128 cols. A (hi/lo bf16) staged in LDS
// in MFMA fragment layout [kblk*4+g][row][8]. M -> LDS -> segment reduce -> atomics.
__global__ __launch_bounds__(512, 1) void edge_mfma_kernel(
    const float* __restrict__ xin,
    const int*   __restrict__ srcS,
    const int*   __restrict__ eperm,
    const int*   __restrict__ dstS,
    const float* __restrict__ ea,
    const ushort* __restrict__ Wh,
    const ushort* __restrict__ Wl,
    const float* __restrict__ bias,
    float* __restrict__ agg,     // pre-zeroed
    int nE, int nTiles)
{
    __shared__ ushort sAh[(KPAD/8) * TILE * 8];   // 40960 B
    __shared__ ushort sAl[(KPAD/8) * TILE * 8];   // 40960 B
    __shared__ float  sM[TILE * 129];             // 66048 B
    __shared__ int    sDst[TILE];

    const int tid  = threadIdx.x;
    const int w    = tid >> 6;
    const int lane = tid & 63;
    const int lg   = lane >> 4;    // k-subgroup 0..3
    const int lr   = lane & 15;    // row (A) / col (B,D)
    const int col  = w * 16 + lr;

    // B fragments in registers: B[k][col], k = kb*32 + lg*8 + j
    s16x8 Bh[5], Bl[5];
    #pragma unroll
    for (int kb = 0; kb < 5; ++kb) {
        #pragma unroll
        for (int j = 0; j < 8; ++j) {
            int k = kb * 32 + lg * 8 + j;
            Bh[kb][j] = (short)Wh[k * N_OUT + col];
            Bl[kb][j] = (short)Wl[k * N_OUT + col];
        }
    }
    const float bv = bias[col];

    const int row = tid >> 2;   // 0..127
    const int c   = tid & 3;    // k-chunk of 32 for x part

    for (int tile = blockIdx.x; tile < nTiles; tile += gridDim.x) {
        const int p0 = tile * TILE;
        const int ne = min(TILE, nE - p0);

        // ---- stage A (gather + split-bf16 convert) ----
        {
            const int p = p0 + row;
            const bool valid = (p < nE);
            const int s = valid ? srcS[p] : 0;
            const float4* xr = (const float4*)(xin + (size_t)s * IN_DIM);
            #pragma unroll
            for (int g = 0; g < 4; ++g) {
                float a[8];
                if (valid) {
                    float4 v0 = xr[c*8 + g*2], v1 = xr[c*8 + g*2 + 1];
                    a[0]=v0.x; a[1]=v0.y; a[2]=v0.z; a[3]=v0.w;
                    a[4]=v1.x; a[5]=v1.y; a[6]=v1.z; a[7]=v1.w;
                } else {
                    #pragma unroll
                    for (int j = 0; j < 8; ++j) a[j] = 0.0f;
                }
                s16x8 hv, lv;
                #pragma unroll
                for (int j = 0; j < 8; ++j) {
                    ushort h = f2bf(a[j]);
                    hv[j] = (short)h;
                    lv[j] = (short)f2bf(a[j] - bf2f(h));
                }
                const int base = ((c*4 + g) * TILE + row) * 8;
                *(s16x8*)&sAh[base] = hv;
                *(s16x8*)&sAl[base] = lv;
            }
            if (c == 0) {   // edge_attr (kblk 4: 16 real + 16 pad)
                const int e = valid ? eperm[p] : 0;
                const float4* er = (const float4*)(ea + (size_t)e * EDGE_D);
                float a[16];
                if (valid) {
                    float4 v0 = er[0], v1 = er[1], v2 = er[2], v3 = er[3];
                    a[0]=v0.x; a[1]=v0.y; a[2]=v0.z; a[3]=v0.w;
                    a[4]=v1.x; a[5]=v1.y; a[6]=v1.z; a[7]=v1.w;
                    a[8]=v2.x; a[9]=v2.y; a[10]=v2.z; a[11]=v2.w;
                    a[12]=v3.x; a[13]=v3.y; a[14]=v3.z; a[15]=v3.w;
                } else {
                    #pragma unroll
                    for (int j = 0; j < 16; ++j) a[j] = 0.0f;
                }
                #pragma unroll
                for (int g = 0; g < 2; ++g) {
                    s16x8 hv, lv;
                    #pragma unroll
                    for (int j = 0; j < 8; ++j) {
                        float f = a[g*8 + j];
                        ushort h = f2bf(f);
                        hv[j] = (short)h;
                        lv[j] = (short)f2bf(f - bf2f(h));
                    }
                    const int base = ((16 + g) * TILE + row) * 8;
                    *(s16x8*)&sAh[base] = hv;
                    *(s16x8*)&sAl[base] = lv;
                }
                s16x8 z = {0,0,0,0,0,0,0,0};
                *(s16x8*)&sAh[(18*TILE + row)*8] = z;
                *(s16x8*)&sAl[(18*TILE + row)*8] = z;
                *(s16x8*)&sAh[(19*TILE + row)*8] = z;
                *(s16x8*)&sAl[(19*TILE + row)*8] = z;
                sDst[row] = valid ? dstS[p] : 0x7fffffff;
            }
        }
        __syncthreads();

        // ---- MFMA: M = relu(bias + Ah*Bh + Al*Bh + Ah*Bl) ----
        f32x4 acc[8];
        #pragma unroll
        for (int b = 0; b < 8; ++b) acc[b] = (f32x4){bv, bv, bv, bv};

        #pragma unroll
        for (int kb = 0; kb < 5; ++kb) {
            #pragma unroll
            for (int b = 0; b < 8; ++b) {
                const int base = ((kb*4 + lg) * TILE + b*16 + lr) * 8;
                s16x8 ah = *(const s16x8*)&sAh[base];
                s16x8 al = *(const s16x8*)&sAl[base];
                acc[b] = __builtin_amdgcn_mfma_f32_16x16x32_bf16(ah, Bh[kb], acc[b], 0, 0, 0);
                acc[b] = __builtin_amdgcn_mfma_f32_16x16x32_bf16(al, Bh[kb], acc[b], 0, 0, 0);
                acc[b] = __builtin_amdgcn_mfma_f32_16x16x32_bf16(ah, Bl[kb], acc[b], 0, 0, 0);
            }
        }

        // ---- relu -> sM (row = (lane>>4)*4 + r within band, col = lane&15) ----
        #pragma unroll
        for (int b = 0; b < 8; ++b) {
            #pragma unroll
            for (int r = 0; r < 4; ++r) {
                sM[(b*16 + lg*4 + r) * 129 + col] = fmaxf(acc[b][r], 0.0f);
            }
        }
        __syncthreads();

        // ---- segment reduce over sorted dst, one atomic per (segment, col) ----
        {
            const int colr = tid & 127;
            const int q    = tid >> 7;
            const int rb   = q * 32;
            const int re   = min(rb + 32, ne);
            if (rb < ne) {
                int dprev = sDst[rb];
                float sum = sM[rb * 129 + colr];
                for (int r = rb + 1; r < re; ++r) {
                    int d = sDst[r];
                    float v = sM[r * 129 + colr];
                    if (d == dprev) sum += v;
                    else {
                        atomicAdd(&agg[(size_t)dprev * N_OUT + colr], sum);
                        dprev = d; sum = v;
                    }
                }
                atomicAdd(&agg[(size_t)dprev * N_OUT + colr], sum);
            }
        }
        __syncthreads();
    }
}

// ---------------- node update: relu(concat(h, agg/cnt) @ U) ----------------
__global__ __launch_bounds__(512, 2) void node_upd_kernel(
    const float* __restrict__ hin,
    const float* __restrict__ agg,
    const float* __restrict__ cnt,
    const float* __restrict__ U,     // [256][128] row-major
    float* __restrict__ out,
    int nNodes)
{
    __shared__ float4 sU[(K_NODE/4) * N_OUT];          // 131072 B
    __shared__ __align__(16) float sc[4][4][K_NODE];   // 16384 B
    const int tid = threadIdx.x;
    const int g   = tid >> 7;
    const int t   = tid & 127;

    for (int idx = tid; idx < (K_NODE/4)*N_OUT; idx += 512) {
        int k4 = idx >> 7, colu = idx & 127;
        float4 u;
        u.x = U[(k4*4+0)*N_OUT + colu];
        u.y = U[(k4*4+1)*N_OUT + colu];
        u.z = U[(k4*4+2)*N_OUT + colu];
        u.w = U[(k4*4+3)*N_OUT + colu];
        sU[idx] = u;
    }
    __syncthreads();

    const int ngrp = (nNodes + 3) >> 2;
    for (int gbase = blockIdx.x*4; gbase < ngrp; gbase += gridDim.x*4) {
        const int grp = gbase + g;
        const bool active = (grp < ngrp);
        const int i0 = grp * 4;
        const int nn = active ? min(4, nNodes - i0) : 0;

        for (int j = 0; j < nn; ++j) {
            int i = i0 + j;
            sc[g][j][t] = hin[(size_t)i*N_OUT + t];
            float rc = 1.0f / fmaxf(cnt[i], 1.0f);
            sc[g][j][N_OUT + t] = agg[(size_t)i*N_OUT + t] * rc;
        }
        __syncthreads();

        float acc0 = 0.f, acc1 = 0.f, acc2 = 0.f, acc3 = 0.f;
        if (active) {
            const float4* c0 = (const float4*)sc[g][0];
            const float4* c1 = (const float4*)sc[g][1];
            const float4* c2 = (const float4*)sc[g][2];
            const float4* c3 = (const float4*)sc[g][3];
            #pragma unroll
            for (int k4 = 0; k4 < K_NODE/4; ++k4) {
                float4 uv = sU[k4*N_OUT + t];
                float4 a;
                a = c0[k4]; acc0 += a.x*uv.x + a.y*uv.y + a.z*uv.z + a.w*uv.w;
                a = c1[k4]; acc1 += a.x*uv.x + a.y*uv.y + a.z*uv.z + a.w*uv.w;
                a = c2[k4]; acc2 += a.x*uv.x + a.y*uv.y + a.z*uv.z + a.w*uv.w;
                a = c3[k4]; acc3 += a.x*uv.x + a.y*uv.y + a.z*uv.z + a.w*uv.w;
            }
        }

        if (0 < nn) out[(size_t)(i0+0)*N_OUT + t] = fmaxf(acc0, 0.0f);
        if (1 < nn) out[(size_t)(i0+1)*N_OUT + t] = fmaxf(acc1, 0.0f);
        if (2 < nn) out[(size_t)(i0+2)*N_OUT + t] = fmaxf(acc2, 0.0f);
        if (3 < nn) out[(size_t)(i0+3)*N_OUT + t] = fmaxf(acc3, 0.0f);
        __syncthreads();
    }
}

extern "C" void kernel_launch(void* const* d_in, const int* in_sizes, int n_in,
                              void* d_out, int out_size, void* d_ws, size_t ws_size,
                              hipStream_t stream)
{
    const float* x  = (const float*)d_in[0];
    const int*   ei = (const int*)  d_in[1];
    const float* ea = (const float*)d_in[2];
    const float* W1 = (const float*)d_in[3];
    const float* b1 = (const float*)d_in[4];
    const float* U1 = (const float*)d_in[5];
    const float* W2 = (const float*)d_in[6];
    const float* b2 = (const float*)d_in[7];
    const float* U2 = (const float*)d_in[8];

    const int nE     = in_sizes[1] / 2;
    const int nNodes = in_sizes[0] / IN_DIM;
    const int nTiles = (nE + TILE - 1) / TILE;
    const int* srcp = ei;
    const int* dstp = ei + nE;

    char* p = (char*)d_ws;
    auto alloc = [&](size_t bytes) { void* r = (void*)p; p += (bytes + 255) & ~(size_t)255; return r; };

    float*  agg   = (float*) alloc((size_t)nNodes * N_OUT * sizeof(float));
    float*  h     = (float*) alloc((size_t)nNodes * N_OUT * sizeof(float));
    float*  cntf  = (float*) alloc((size_t)nNodes * sizeof(float));
    int*    hist  = (int*)   alloc((size_t)nNodes * sizeof(int));
    int*    rowptr= (int*)   alloc((size_t)(nNodes + 1) * sizeof(int));
    int*    cursor= (int*)   alloc((size_t)nNodes * sizeof(int));
    int*    eperm = (int*)   alloc((size_t)nE * sizeof(int));
    int*    dstS  = (int*)   alloc((size_t)nE * sizeof(int));
    int*    srcS  = (int*)   alloc((size_t)nE * sizeof(int));
    ushort* Wh1   = (ushort*)alloc((size_t)KPAD * N_OUT * sizeof(ushort));
    ushort* Wl1   = (ushort*)alloc((size_t)KPAD * N_OUT * sizeof(ushort));
    ushort* Wh2   = (ushort*)alloc((size_t)KPAD * N_OUT * sizeof(ushort));
    ushort* Wl2   = (ushort*)alloc((size_t)KPAD * N_OUT * sizeof(ushort));
    float*  outp  = (float*)d_out;

    // ---- CSR build + weight prep (once) ----
    hipMemsetAsync(hist,   0, (size_t)nNodes * sizeof(int), stream);
    hipMemsetAsync(cursor, 0, (size_t)nNodes * sizeof(int), stream);
    hist_kernel<<<(nE + 255)/256, 256, 0, stream>>>(dstp, hist, nE);
    scan_kernel<<<1, 1024, 0, stream>>>(hist, rowptr, nNodes);
    scatter_kernel<<<(nE + 255)/256, 256, 0, stream>>>(srcp, dstp, rowptr, cursor,
                                                       eperm, srcS, dstS, nE);
    deg_kernel<<<(nNodes + 255)/256, 256, 0, stream>>>(hist, cntf, nNodes);
    wprep_kernel<<<(KPAD*N_OUT + 255)/256, 256, 0, stream>>>(W1, Wh1, Wl1, IN_DIM + EDGE_D);
    wprep_kernel<<<(KPAD*N_OUT + 255)/256, 256, 0, stream>>>(W2, Wh2, Wl2, N_OUT + EDGE_D);

    auto run_layer = [&](const float* xin, const ushort* Wh, const ushort* Wl,
                         const float* b, const float* U, float* xout) {
        hipMemsetAsync(agg, 0, (size_t)nNodes * N_OUT * sizeof(float), stream);
        edge_mfma_kernel<<<256, 512, 0, stream>>>(xin, srcS, eperm, dstS, ea,
                                                  Wh, Wl, b, agg, nE, nTiles);
        node_upd_kernel<<<256, 512, 0, stream>>>(xin, agg, cntf, U, xout, nNodes);
    };

    run_layer(x, Wh1, Wl1, b1, U1, h);     // conv1
    run_layer(h, Wh2, Wl2, b2, U2, h);     // conv2 (in-place safe per-row)
    run_layer(h, Wh2, Wl2, b2, U2, outp);  // conv3 -> d_out
}

// Round 4
// 782.194 us; speedup vs baseline: 5.0757x; 1.3116x over previous
//
#include <hip/hip_runtime.h>

#define N_OUT   128
#define IN_DIM  128
#define EDGE_D  16
#define TILE    128
#define NKG_E   20    // edge kgroups of 8 k (160 = 144 padded)
#define NKG_N   32    // node kgroups (256 k)
#define SM_S    132   // sM row stride in floats (132*4 % 128B -> conflict-free)

typedef short  s16x8 __attribute__((ext_vector_type(8)));
typedef float  f32x4 __attribute__((ext_vector_type(4)));

__device__ __forceinline__ ushort f2bf(float f) {
    unsigned u = __float_as_uint(f);
    return (ushort)((u + 0x7FFFu + ((u >> 16) & 1u)) >> 16);   // RNE
}
__device__ __forceinline__ float bf2f(ushort h) {
    return __uint_as_float(((unsigned)h) << 16);
}

// ---------------- one-time prep ----------------
__global__ void split_kernel(const float* __restrict__ x, ushort* __restrict__ xh,
                             ushort* __restrict__ xl, int n) {
    int i = blockIdx.x * blockDim.x + threadIdx.x;
    if (i < n) {
        float f = x[i];
        ushort h = f2bf(f);
        xh[i] = h;
        xl[i] = f2bf(f - bf2f(h));
    }
}

// W [K][128] f32 -> hi/lo bf16 in MFMA B-frag layout: [(k/8)*128 + col]*8 + (k&7)
__global__ void wprep_kernel(const float* __restrict__ W, ushort* __restrict__ Whf,
                             ushort* __restrict__ Wlf, int K, int KPAD) {
    int i = blockIdx.x * blockDim.x + threadIdx.x;
    if (i >= KPAD * N_OUT) return;
    int k = i >> 7, col = i & 127;
    float f = (k < K) ? W[k * N_OUT + col] : 0.0f;
    ushort h = f2bf(f);
    int d = ((k >> 3) * N_OUT + col) * 8 + (k & 7);
    Whf[d] = h;
    Wlf[d] = f2bf(f - bf2f(h));
}

// ---------------- CSR build (once; src/dst are layer-invariant) ----------------
__global__ void hist_kernel(const int* __restrict__ dst, int* __restrict__ hist, int nE) {
    int e = blockIdx.x * blockDim.x + threadIdx.x;
    if (e < nE) atomicAdd(&hist[dst[e]], 1);
}

__global__ void scan_kernel(const int* __restrict__ hist, int* __restrict__ rowptr, int n) {
    __shared__ int buf[1024];
    __shared__ int carry;
    if (threadIdx.x == 0) carry = 0;
    __syncthreads();
    int nch = (n + 1023) >> 10;
    for (int ch = 0; ch < nch; ++ch) {
        int i = (ch << 10) + threadIdx.x;
        int v = (i < n) ? hist[i] : 0;
        buf[threadIdx.x] = v;
        __syncthreads();
        for (int off = 1; off < 1024; off <<= 1) {
            int t = (threadIdx.x >= (unsigned)off) ? buf[threadIdx.x - off] : 0;
            __syncthreads();
            buf[threadIdx.x] += t;
            __syncthreads();
        }
        if (i < n) rowptr[i] = carry + buf[threadIdx.x] - v;   // exclusive
        __syncthreads();
        if (threadIdx.x == 1023) carry += buf[1023];
        __syncthreads();
    }
}

__global__ void scatter_kernel(const int* __restrict__ src, const int* __restrict__ dst,
                               const int* __restrict__ rowptr, int* __restrict__ cursor,
                               int* __restrict__ eperm, int* __restrict__ srcS,
                               int* __restrict__ dstS, int nE) {
    int e = blockIdx.x * blockDim.x + threadIdx.x;
    if (e < nE) {
        int d = dst[e];
        int pos = rowptr[d] + atomicAdd(&cursor[d], 1);
        eperm[pos] = e;
        dstS[pos]  = d;
        srcS[pos]  = src[e];
    }
}

__global__ void deg_kernel(const int* __restrict__ hist, float* __restrict__ cntf, int n) {
    int i = blockIdx.x * blockDim.x + threadIdx.x;
    if (i < n) cntf[i] = (float)hist[i];
}

// ---------------- edge GEMM (split-bf16 MFMA, pipelined) + segment-reduce ----------------
// 512 thr = 8 waves. Wave w owns cols 16w..16w+15; W frags in registers.
// Staging: row = tid&127, c = tid>>7 -> wave writes 1024B contiguous LDS (conflict-free).
// Register prefetch of next tile's gather overlaps MFMA + reduce of current tile.
__global__ __launch_bounds__(512, 1) void edge_mfma_kernel(
    const ushort* __restrict__ xh, const ushort* __restrict__ xl,
    const int*   __restrict__ srcS,
    const int*   __restrict__ eperm,
    const int*   __restrict__ dstS,
    const float* __restrict__ ea,
    const ushort* __restrict__ Whf,
    const ushort* __restrict__ Wlf,
    const float* __restrict__ bias,
    float* __restrict__ agg,     // pre-zeroed
    int nE, int nTiles)
{
    __shared__ ushort sAh[NKG_E * TILE * 8];   // 40960 B
    __shared__ ushort sAl[NKG_E * TILE * 8];   // 40960 B
    __shared__ float  sM[TILE * SM_S];         // 67584 B
    __shared__ int    sDst[TILE];              // total 150016 B

    const int tid  = threadIdx.x;
    const int w    = tid >> 6;
    const int lane = tid & 63;
    const int lg   = lane >> 4;
    const int lr   = lane & 15;
    const int col  = w * 16 + lr;

    // B fragments (vector loads from frag-layout weights)
    s16x8 Bh[5], Bl[5];
    #pragma unroll
    for (int kb = 0; kb < 5; ++kb) {
        int kg = kb * 4 + lg;
        Bh[kb] = *(const s16x8*)&Whf[(kg * N_OUT + col) * 8];
        Bl[kb] = *(const s16x8*)&Wlf[(kg * N_OUT + col) * 8];
    }
    const float bv = bias[col];

    // zero the static pad kgroups 18,19 once
    if (tid < 256) {
        int kg = 18 + (tid >> 7), r = tid & 127;
        s16x8 z = {0,0,0,0,0,0,0,0};
        *(s16x8*)&sAh[(kg * TILE + r) * 8] = z;
        *(s16x8*)&sAl[(kg * TILE + r) * 8] = z;
    }

    const int row = tid & 127;   // tile row this thread stages
    const int c   = tid >> 7;    // k-quarter (32 k) of the x part

    s16x8 rh[4], rl[4];
    float4 re4[4];
    int rdst = 0x7fffffff;

    auto prefetch = [&](int tile) {
        int p = tile * TILE + row;
        bool valid = (p < nE);
        int s = valid ? srcS[p] : 0;
        const s16x8* ph = (const s16x8*)(xh + (size_t)s * IN_DIM + c * 32);
        const s16x8* pl = (const s16x8*)(xl + (size_t)s * IN_DIM + c * 32);
        #pragma unroll
        for (int g = 0; g < 4; ++g) { rh[g] = ph[g]; rl[g] = pl[g]; }
        if (c == 0) {
            int e = valid ? eperm[p] : 0;
            const float4* pe = (const float4*)(ea + (size_t)e * EDGE_D);
            #pragma unroll
            for (int g = 0; g < 4; ++g) re4[g] = pe[g];
            rdst = valid ? dstS[p] : 0x7fffffff;
        }
    };

    prefetch(blockIdx.x);

    for (int tile = blockIdx.x; tile < nTiles; tile += gridDim.x) {
        __syncthreads();   // prev MFMA reads of sA + reduce reads of sM/sDst done
        #pragma unroll
        for (int g = 0; g < 4; ++g) {
            *(s16x8*)&sAh[((c*4 + g) * TILE + row) * 8] = rh[g];
            *(s16x8*)&sAl[((c*4 + g) * TILE + row) * 8] = rl[g];
        }
        if (c == 0) {   // edge_attr: convert 16 f32 -> hi/lo (kgroups 16,17)
            float a[16] = {re4[0].x, re4[0].y, re4[0].z, re4[0].w,
                           re4[1].x, re4[1].y, re4[1].z, re4[1].w,
                           re4[2].x, re4[2].y, re4[2].z, re4[2].w,
                           re4[3].x, re4[3].y, re4[3].z, re4[3].w};
            #pragma unroll
            for (int g = 0; g < 2; ++g) {
                s16x8 hv, lv;
                #pragma unroll
                for (int j = 0; j < 8; ++j) {
                    float f = a[g*8 + j];
                    ushort h = f2bf(f);
                    hv[j] = (short)h;
                    lv[j] = (short)f2bf(f - bf2f(h));
                }
                *(s16x8*)&sAh[((16 + g) * TILE + row) * 8] = hv;
                *(s16x8*)&sAl[((16 + g) * TILE + row) * 8] = lv;
            }
            sDst[row] = rdst;
        }
        __syncthreads();   // A-tile visible

        prefetch(tile + gridDim.x);   // global loads overlap MFMA + reduce

        f32x4 acc[8];
        #pragma unroll
        for (int b = 0; b < 8; ++b) acc[b] = (f32x4){bv, bv, bv, bv};

        #pragma unroll
        for (int kb = 0; kb < 5; ++kb) {
            #pragma unroll
            for (int b = 0; b < 8; ++b) {
                const int base = ((kb*4 + lg) * TILE + b*16 + lr) * 8;
                s16x8 ah = *(const s16x8*)&sAh[base];
                s16x8 al = *(const s16x8*)&sAl[base];
                acc[b] = __builtin_amdgcn_mfma_f32_16x16x32_bf16(ah, Bh[kb], acc[b], 0, 0, 0);
                acc[b] = __builtin_amdgcn_mfma_f32_16x16x32_bf16(al, Bh[kb], acc[b], 0, 0, 0);
                acc[b] = __builtin_amdgcn_mfma_f32_16x16x32_bf16(ah, Bl[kb], acc[b], 0, 0, 0);
            }
        }

        #pragma unroll
        for (int b = 0; b < 8; ++b) {
            #pragma unroll
            for (int r = 0; r < 4; ++r) {
                sM[(b*16 + lg*4 + r) * SM_S + col] = fmaxf(acc[b][r], 0.0f);
            }
        }
        __syncthreads();

        // segment reduce over sorted dst, one atomic per (segment-chunk, col)
        {
            const int ne   = min(TILE, nE - tile * TILE);
            const int colr = tid & 127;
            const int q    = tid >> 7;
            const int rb   = q * 32;
            const int rend = min(rb + 32, ne);
            if (rb < ne) {
                int dprev = sDst[rb];
                float sum = sM[rb * SM_S + colr];
                for (int r = rb + 1; r < rend; ++r) {
                    int d = sDst[r];
                    float v = sM[r * SM_S + colr];
                    if (d == dprev) sum += v;
                    else {
                        atomicAdd(&agg[(size_t)dprev * N_OUT + colr], sum);
                        dprev = d; sum = v;
                    }
                }
                atomicAdd(&agg[(size_t)dprev * N_OUT + colr], sum);
            }
        }
    }
}

// ---------------- node update (split-bf16 MFMA): relu(concat(h, agg/cnt) @ U) ----------------
// Reads h as bf16 hi/lo pair; writes next layer's hi/lo (or f32 out on last layer).
__global__ __launch_bounds__(512, 1) void node_mfma_kernel(
    const ushort* __restrict__ hh, const ushort* __restrict__ hl,
    const float* __restrict__ agg, const float* __restrict__ cnt,
    const ushort* __restrict__ Uhf, const ushort* __restrict__ Ulf,
    float* __restrict__ outf, ushort* __restrict__ outh, ushort* __restrict__ outl,
    int lastLayer, int nNodes, int nTiles)
{
    __shared__ ushort sAh[NKG_N * TILE * 8];   // 65536 B
    __shared__ ushort sAl[NKG_N * TILE * 8];   // 65536 B

    const int tid  = threadIdx.x;
    const int w    = tid >> 6;
    const int lane = tid & 63;
    const int lg   = lane >> 4;
    const int lr   = lane & 15;
    const int col  = w * 16 + lr;

    s16x8 Bh[8], Bl[8];
    #pragma unroll
    for (int kb = 0; kb < 8; ++kb) {
        int kg = kb * 4 + lg;
        Bh[kb] = *(const s16x8*)&Uhf[(kg * N_OUT + col) * 8];
        Bl[kb] = *(const s16x8*)&Ulf[(kg * N_OUT + col) * 8];
    }

    const int row = tid & 127;
    const int c   = tid >> 7;    // k-quarter of 64 k

    for (int tile = blockIdx.x; tile < nTiles; tile += gridDim.x) {
        __syncthreads();
        const int i = tile * TILE + row;
        const bool valid = (i < nNodes);
        const int ii = valid ? i : 0;
        if (c < 2) {   // h part: kgroups c*8 .. c*8+7 (direct bf16 copy)
            const s16x8* ph = (const s16x8*)(hh + (size_t)ii * N_OUT + c * 64);
            const s16x8* pl = (const s16x8*)(hl + (size_t)ii * N_OUT + c * 64);
            #pragma unroll
            for (int g = 0; g < 8; ++g) {
                *(s16x8*)&sAh[((c*8 + g) * TILE + row) * 8] = ph[g];
                *(s16x8*)&sAl[((c*8 + g) * TILE + row) * 8] = pl[g];
            }
        } else {       // agg part: scale by 1/deg, split
            float rc = 1.0f / fmaxf(cnt[ii], 1.0f);
            const float4* pa = (const float4*)(agg + (size_t)ii * N_OUT + (c - 2) * 64);
            #pragma unroll
            for (int g = 0; g < 8; ++g) {
                float4 v0 = pa[g*2], v1 = pa[g*2 + 1];
                float a[8] = {v0.x, v0.y, v0.z, v0.w, v1.x, v1.y, v1.z, v1.w};
                s16x8 hv, lv;
                #pragma unroll
                for (int j = 0; j < 8; ++j) {
                    float f = a[j] * rc;
                    ushort h = f2bf(f);
                    hv[j] = (short)h;
                    lv[j] = (short)f2bf(f - bf2f(h));
                }
                int kg = 16 + (c - 2) * 8 + g;
                *(s16x8*)&sAh[(kg * TILE + row) * 8] = hv;
                *(s16x8*)&sAl[(kg * TILE + row) * 8] = lv;
            }
        }
        __syncthreads();

        f32x4 acc[8];
        #pragma unroll
        for (int b = 0; b < 8; ++b) acc[b] = (f32x4){0.f, 0.f, 0.f, 0.f};

        #pragma unroll
        for (int kb = 0; kb < 8; ++kb) {
            #pragma unroll
            for (int b = 0; b < 8; ++b) {
                const int base = ((kb*4 + lg) * TILE + b*16 + lr) * 8;
                s16x8 ah = *(const s16x8*)&sAh[base];
                s16x8 al = *(const s16x8*)&sAl[base];
                acc[b] = __builtin_amdgcn_mfma_f32_16x16x32_bf16(ah, Bh[kb], acc[b], 0, 0, 0);
                acc[b] = __builtin_amdgcn_mfma_f32_16x16x32_bf16(al, Bh[kb], acc[b], 0, 0, 0);
                acc[b] = __builtin_amdgcn_mfma_f32_16x16x32_bf16(ah, Bl[kb], acc[b], 0, 0, 0);
            }
        }

        #pragma unroll
        for (int b = 0; b < 8; ++b) {
            #pragma unroll
            for (int r = 0; r < 4; ++r) {
                int rr = tile * TILE + b*16 + lg*4 + r;
                if (rr < nNodes) {
                    float v = fmaxf(acc[b][r], 0.0f);
                    if (lastLayer) {
                        outf[(size_t)rr * N_OUT + col] = v;
                    } else {
                        ushort h = f2bf(v);
                        outh[(size_t)rr * N_OUT + col] = h;
                        outl[(size_t)rr * N_OUT + col] = f2bf(v - bf2f(h));
                    }
                }
            }
        }
    }
}

extern "C" void kernel_launch(void* const* d_in, const int* in_sizes, int n_in,
                              void* d_out, int out_size, void* d_ws, size_t ws_size,
                              hipStream_t stream)
{
    const float* x  = (const float*)d_in[0];
    const int*   ei = (const int*)  d_in[1];
    const float* ea = (const float*)d_in[2];
    const float* W1 = (const float*)d_in[3];
    const float* b1 = (const float*)d_in[4];
    const float* U1 = (const float*)d_in[5];
    const float* W2 = (const float*)d_in[6];
    const float* b2 = (const float*)d_in[7];
    const float* U2 = (const float*)d_in[8];

    const int nE      = in_sizes[1] / 2;
    const int nNodes  = in_sizes[0] / IN_DIM;
    const int nTilesE = (nE + TILE - 1) / TILE;
    const int nTilesN = (nNodes + TILE - 1) / TILE;
    const int* srcp = ei;
    const int* dstp = ei + nE;

    char* p = (char*)d_ws;
    auto alloc = [&](size_t bytes) { void* r = (void*)p; p += (bytes + 255) & ~(size_t)255; return r; };

    float*  agg   = (float*) alloc((size_t)nNodes * N_OUT * sizeof(float));
    ushort* xhh   = (ushort*)alloc((size_t)nNodes * N_OUT * sizeof(ushort));
    ushort* xll   = (ushort*)alloc((size_t)nNodes * N_OUT * sizeof(ushort));
    float*  cntf  = (float*) alloc((size_t)nNodes * sizeof(float));
    int*    hist  = (int*)   alloc((size_t)nNodes * sizeof(int));
    int*    rowptr= (int*)   alloc((size_t)(nNodes + 1) * sizeof(int));
    int*    cursor= (int*)   alloc((size_t)nNodes * sizeof(int));
    int*    eperm = (int*)   alloc((size_t)nE * sizeof(int));
    int*    dstS  = (int*)   alloc((size_t)nE * sizeof(int));
    int*    srcS  = (int*)   alloc((size_t)nE * sizeof(int));
    ushort* Whf1  = (ushort*)alloc((size_t)NKG_E * 8 * N_OUT * sizeof(ushort));
    ushort* Wlf1  = (ushort*)alloc((size_t)NKG_E * 8 * N_OUT * sizeof(ushort));
    ushort* Whf2  = (ushort*)alloc((size_t)NKG_E * 8 * N_OUT * sizeof(ushort));
    ushort* Wlf2  = (ushort*)alloc((size_t)NKG_E * 8 * N_OUT * sizeof(ushort));
    ushort* Uhf1  = (ushort*)alloc((size_t)NKG_N * 8 * N_OUT * sizeof(ushort));
    ushort* Ulf1  = (ushort*)alloc((size_t)NKG_N * 8 * N_OUT * sizeof(ushort));
    ushort* Uhf2  = (ushort*)alloc((size_t)NKG_N * 8 * N_OUT * sizeof(ushort));
    ushort* Ulf2  = (ushort*)alloc((size_t)NKG_N * 8 * N_OUT * sizeof(ushort));
    float*  outp  = (float*)d_out;

    // ---- one-time prep: CSR, degree, weight frags, x split ----
    hipMemsetAsync(hist,   0, (size_t)nNodes * sizeof(int), stream);
    hipMemsetAsync(cursor, 0, (size_t)nNodes * sizeof(int), stream);
    hist_kernel<<<(nE + 255)/256, 256, 0, stream>>>(dstp, hist, nE);
    scan_kernel<<<1, 1024, 0, stream>>>(hist, rowptr, nNodes);
    scatter_kernel<<<(nE + 255)/256, 256, 0, stream>>>(srcp, dstp, rowptr, cursor,
                                                       eperm, srcS, dstS, nE);
    deg_kernel<<<(nNodes + 255)/256, 256, 0, stream>>>(hist, cntf, nNodes);
    wprep_kernel<<<(NKG_E*8*N_OUT + 255)/256, 256, 0, stream>>>(W1, Whf1, Wlf1, IN_DIM + EDGE_D, NKG_E*8);
    wprep_kernel<<<(NKG_E*8*N_OUT + 255)/256, 256, 0, stream>>>(W2, Whf2, Wlf2, N_OUT + EDGE_D, NKG_E*8);
    wprep_kernel<<<(NKG_N*8*N_OUT + 255)/256, 256, 0, stream>>>(U1, Uhf1, Ulf1, NKG_N*8, NKG_N*8);
    wprep_kernel<<<(NKG_N*8*N_OUT + 255)/256, 256, 0, stream>>>(U2, Uhf2, Ulf2, NKG_N*8, NKG_N*8);
    split_kernel<<<((nNodes*N_OUT) + 255)/256, 256, 0, stream>>>(x, xhh, xll, nNodes * IN_DIM);

    auto run_layer = [&](const ushort* Whf, const ushort* Wlf, const float* b,
                         const ushort* Uhf, const ushort* Ulf, int last) {
        hipMemsetAsync(agg, 0, (size_t)nNodes * N_OUT * sizeof(float), stream);
        edge_mfma_kernel<<<256, 512, 0, stream>>>(xhh, xll, srcS, eperm, dstS, ea,
                                                  Whf, Wlf, b, agg, nE, nTilesE);
        node_mfma_kernel<<<nTilesN, 512, 0, stream>>>(xhh, xll, agg, cntf, Uhf, Ulf,
                                                      outp, xhh, xll, last, nNodes, nTilesN);
    };

    run_layer(Whf1, Wlf1, b1, Uhf1, Ulf1, 0);   // conv1 -> (xhh,xll)
    run_layer(Whf2, Wlf2, b2, Uhf2, Ulf2, 0);   // conv2 -> (xhh,xll)
    run_layer(Whf2, Wlf2, b2, Uhf2, Ulf2, 1);   // conv3 -> d_out (f32)
}